// Round 8
// baseline (153.298 us; speedup 1.0000x reference)
//
#include <hip/hip_runtime.h>
#include <math.h>

// Problem constants: B,H,K,L,V = 4096,1024,10,64,80
constexpr int Bn = 4096;
constexpr int Hn = 1024;
constexpr int Kn = 10;
constexpr int Ln = 64;
constexpr int Vn = 80;
constexpr int NJ = 3 * Kn;   // 30
constexpr int R  = 8;        // batch rows per block (2x R0)
constexpr int NT = 512;      // 8 waves (2x R0)
// grid = Bn/R = 512 blocks -> 2 blocks/CU, 16 waves/CU. LDS ~51 KB/block.
//
// Rationale (round-8 audit): the session-invariant cost was GEMM instruction
// issue: R0 spent ~8192 ds_read_b128 + 8192 scalar W-loads PER CU (~30 us of
// issue). Fattening the block 4x (R=8, NT=512) amortizes the same W-columns
// over 4x more rows: per CU now 2048 ds + 1024 W-loads (~6 us). The einsum
// is R0's measured-best form, verbatim per 4-row half-block.

__global__ __launch_bounds__(NT) void window_fused(
    const float* __restrict__ x,      // [B,H]
    const float* __restrict__ chars,  // [B,L,V]
    const float* __restrict__ W,      // [H,3K]
    const float* __restrict__ bias,   // [3K]
    float* __restrict__ out)          // [B,V]
{
    __shared__ float4 xs4[R * Hn / 4];   // 32 KB x stage; reused as cpart later
    __shared__ float  part[R * 512];     // 16 KB GEMM partials [r][g*32+j]
    __shared__ float  abk[R * NJ];       // 960 B
    __shared__ float  phi_s[R * Ln];     // 2 KB

    const int t    = threadIdx.x;
    const int row0 = blockIdx.x * R;

    // ---- Stage x rows into LDS (coalesced float4: 2048 float4 / 512 thr) ----
    const float4* xg4 = (const float4*)x + (size_t)row0 * (Hn / 4);
#pragma unroll
    for (int i = 0; i < 4; ++i)
        xs4[i * NT + t] = xg4[i * NT + t];
    __syncthreads();

    // ---- GEMM partials: part[r][g*32+j] = sum_{h in g's 64} x[r][h]*W[h][j]
    //      j = t&31 (30 active), g = t>>5 in 0..15 covers h in [64g, 64g+64).
    //      Per thread: 64 scalar W loads (120 B/wave-seg, L2) + 128 ds_b128.
    {
        const int j = t & 31;
        const int g = t >> 5;
        float acc[R];
#pragma unroll
        for (int r = 0; r < R; ++r) acc[r] = 0.f;
        if (j < NJ) {
            const float* Wp = W + j;
            const int h0 = g * 64;
#pragma unroll 4
            for (int ii = 0; ii < 64; ii += 4) {
                const int h  = h0 + ii;
                const int h4 = h >> 2;
                float w0 = Wp[(h + 0) * NJ];
                float w1 = Wp[(h + 1) * NJ];
                float w2 = Wp[(h + 2) * NJ];
                float w3 = Wp[(h + 3) * NJ];
#pragma unroll
                for (int r = 0; r < R; ++r) {
                    float4 v = xs4[r * 256 + h4];   // LDS broadcast across j
                    acc[r] += w0 * v.x + w1 * v.y + w2 * v.z + w3 * v.w;
                }
            }
        }
#pragma unroll
        for (int r = 0; r < R; ++r) part[r * 512 + g * 32 + j] = acc[r];
    }
    __syncthreads();

    // ---- Reduce 16 h-groups + bias, exp -> alpha/beta/kappa ----
    if (t < R * NJ) {  // 240 threads
        const int r = t / NJ, jj = t % NJ;
        float s = bias[jj];
#pragma unroll
        for (int gg = 0; gg < 16; ++gg) s += part[r * 512 + gg * 32 + jj];
        abk[r * NJ + jj] = __expf(s);
    }
    __syncthreads();

    // ---- phi[r][l] = sum_k alpha*exp(-beta*(kappa-l)^2): 512 thr = 8r x 64l ----
    {
        const int r = t >> 6, l = t & 63;
        const float lf = (float)l;
        const float* ab = abk + r * NJ;
        float ph = 0.f;
#pragma unroll
        for (int k = 0; k < Kn; ++k) {
            float a  = ab[k];
            float bt = ab[Kn + k];
            float kp = ab[2 * Kn + k];
            float d  = kp - lf;
            ph += a * __expf(-bt * d * d);
        }
        phi_s[r * Ln + l] = ph;
    }
    __syncthreads();

    // ---- Einsum: R0's measured-best structure, per 4-row half-block.
    //      half = t/256 handles rows half*4..half*4+3; tt<240 active per half.
    float4* cpart = xs4;   // x dead; 2*960 = 1920 float4 = 30 KB of the 32 KB
    const float4* c4 = (const float4*)chars;
    const int half = t >> 8;          // 0 or 1
    const int tt   = t & 255;
    if (tt < 240) {
        const int v4  = tt % 20;      // float4 column
        const int g12 = tt / 20;      // 12 l-groups
        const int r0  = row0 + half * 4;
        float4 s0 = make_float4(0.f, 0.f, 0.f, 0.f);
        float4 s1 = s0, s2 = s0, s3 = s0;
        for (int l = g12; l < Ln; l += 12) {
            const int off = l * 20 + v4;
            float4 cA = c4[(size_t)(r0 + 0) * 1280 + off];
            float4 cB = c4[(size_t)(r0 + 1) * 1280 + off];
            float4 cC = c4[(size_t)(r0 + 2) * 1280 + off];
            float4 cD = c4[(size_t)(r0 + 3) * 1280 + off];
            const float* ph = phi_s + half * 4 * Ln;
            float p0 = ph[0 * Ln + l];
            float p1 = ph[1 * Ln + l];
            float p2 = ph[2 * Ln + l];
            float p3 = ph[3 * Ln + l];
            s0.x += p0 * cA.x; s0.y += p0 * cA.y; s0.z += p0 * cA.z; s0.w += p0 * cA.w;
            s1.x += p1 * cB.x; s1.y += p1 * cB.y; s1.z += p1 * cB.z; s1.w += p1 * cB.w;
            s2.x += p2 * cC.x; s2.y += p2 * cC.y; s2.z += p2 * cC.z; s2.w += p2 * cC.w;
            s3.x += p3 * cD.x; s3.y += p3 * cD.y; s3.z += p3 * cD.z; s3.w += p3 * cD.w;
        }
        float4* cp = cpart + half * 960;
        cp[(0 * 12 + g12) * 20 + v4] = s0;
        cp[(1 * 12 + g12) * 20 + v4] = s1;
        cp[(2 * 12 + g12) * 20 + v4] = s2;
        cp[(3 * 12 + g12) * 20 + v4] = s3;
    }
    __syncthreads();

    // ---- Final reduce: 160 threads, one float4 of out each ----
    if (t < R * 20) {
        const int r  = t / 20;        // 0..7
        const int vv = t % 20;
        const float4* cp = cpart + (r / 4) * 960;
        const int rl = r & 3;
        float4 s = make_float4(0.f, 0.f, 0.f, 0.f);
#pragma unroll
        for (int gg = 0; gg < 12; ++gg) {
            float4 p = cp[(rl * 12 + gg) * 20 + vv];
            s.x += p.x; s.y += p.y; s.z += p.z; s.w += p.w;
        }
        ((float4*)out)[(size_t)(row0 + r) * 20 + vv] = s;
    }
}

extern "C" void kernel_launch(void* const* d_in, const int* in_sizes, int n_in,
                              void* d_out, int out_size, void* d_ws, size_t ws_size,
                              hipStream_t stream) {
    const float* x     = (const float*)d_in[0];
    const float* chars = (const float*)d_in[1];
    const float* W     = (const float*)d_in[2];
    const float* bias  = (const float*)d_in[3];
    float* out = (float*)d_out;

    window_fused<<<Bn / R, NT, 0, stream>>>(x, chars, W, bias, out);
}